// Round 15
// baseline (87.183 us; speedup 1.0000x reference)
//
#include <hip/hip_runtime.h>

// RetinaNet matcher: gt_boxes [B=8, G=64, 4] f32, anchors [A=120000, 4] f32.
// Outputs (concat in d_out, f32): matched_idxs [B,A] (as float), matched_vals [B,A].
//
// Numerics: bit-exact vs np (absmax 0.0 R5-R14). opaque() barriers on every
// mul result -> no FMA-contraction site. div_rn() = correctly-rounded divide
// for mid-range operands (== v_div expansion with scale==1). argmax
// tie-break = first g (strict >). IoU >= 0 -> uint atomicMax bit-exact.
//
// R15: occupancy fix for pass1. R14 ran 944 blocks = 2.2 waves/SIMD; the
// 8-op serial div chain starves the SIMD at that residency (busy 80% but
// ~2.4x the issue-slot floor). Split the g-dim: each block does one 32-g
// half x 1024 anchors -> 1888 blocks, butterfly total and per-pair cost
// UNCHANGED (R12's mistake avoided). vmax/amax merge across the two halves
// via packed u64 atomicMax: key = (bits(q) << 32) | ~g  (q>=0 -> monotone;
// tie -> smaller g wins = np.argmax first-tie). Chain q <= m_halfblock <=
// hpg keeps the E-mask factorization exact per half.

static constexpr int G = 64;

__device__ __forceinline__ float opaque(float x) {
    asm volatile("" : "+v"(x));  // no-op; blocks FMA contraction across x
    return x;
}

__device__ __forceinline__ int vindex(int i) {
    asm volatile("" : "+v"(i));  // force VGPR residency; defeats scalarization
    return i;
}

__device__ __forceinline__ float box_area(float x1, float y1, float x2, float y2) {
    return opaque(__fmul_rn(__fsub_rn(x2, x1), __fsub_rn(y2, y1)));
}

__device__ __forceinline__ float inter_area(float gx1, float gy1, float gx2, float gy2,
                                            float ax1, float ay1, float ax2, float ay2) {
    float ltx = fmaxf(gx1, ax1);
    float lty = fmaxf(gy1, ay1);
    float rbx = fminf(gx2, ax2);
    float rby = fminf(gy2, ay2);
    float w = fmaxf(__fsub_rn(rbx, ltx), 0.0f);
    float h = fmaxf(__fsub_rn(rby, lty), 0.0f);
    return opaque(__fmul_rn(w, h));
}

// Correctly-rounded f32 divide for mid-range operands (no denormal/overflow).
__device__ __forceinline__ float div_rn(float n, float d) {
    float r = __builtin_amdgcn_rcpf(d);
    float e = fmaf(-d, r, 1.0f);
    r = fmaf(e, r, r);
    float q = __fmul_rn(n, r);
    float s = fmaf(-d, q, n);
    q = fmaf(s, r, q);
    s = fmaf(-d, q, n);
    q = fmaf(s, r, q);
    return q;
}

#define DPP_MAX_STAGE(x, ctrl)                                                   \
    do {                                                                         \
        int _yi = __builtin_amdgcn_update_dpp(__float_as_int(x),                 \
                                              __float_as_int(x), (ctrl),         \
                                              0xf, 0xf, false);                  \
        (x) = fmaxf((x), __int_as_float(_yi));                                   \
    } while (0)

// Full wave64 max; result valid in lane 63.
__device__ __forceinline__ float wave_max_lane63(float x) {
    DPP_MAX_STAGE(x, 0xB1);   // quad_perm xor1
    DPP_MAX_STAGE(x, 0x4E);   // quad_perm xor2
    DPP_MAX_STAGE(x, 0x141);  // row_half_mirror
    DPP_MAX_STAGE(x, 0x140);  // row_mirror
    DPP_MAX_STAGE(x, 0x142);  // row_bcast15
    DPP_MAX_STAGE(x, 0x143);  // row_bcast31
    return x;
}

// hpg[i] = 0 bits (+0.0f) and gt-area cache for all (b,g).
__global__ void k_init(const float* __restrict__ gt, unsigned int* __restrict__ hpg,
                       float* __restrict__ gab, int BG) {
    int i = blockIdx.x * 256 + threadIdx.x;
    if (i < BG) {
        hpg[i] = 0u;
        float4 gb = ((const float4*)gt)[i];
        gab[i] = box_area(gb.x, gb.y, gb.z, gb.w);
    }
}

// Pass 1: block = (chunk of 1024 anchors, half of 32 g's, b).
// 4 anchors/thread, g-outer, DPP wave max, LDS half-block max.
// STORE: per-anchor packed (vmax,amax) u64 atomicMax merge; dump sred[32].
// Grid: (nchunks, 2, B), block 256.
template <bool STORE>
__global__ __launch_bounds__(256, 8)
void pass1_k(const float* __restrict__ gt,
             const float* __restrict__ anchors,
             const float* __restrict__ gab,
             unsigned int* __restrict__ hpg,
             unsigned int* __restrict__ sredg,
             unsigned long long* __restrict__ packed,
             int A, int nchunks) {
    const int b = blockIdx.z;
    const int g0 = blockIdx.y * 32;
    const int t = threadIdx.x;

    __shared__ unsigned int sred[32];
    if (t < 32) sred[t] = 0u;
    __syncthreads();

    const int base = blockIdx.x * 1024;
    float ax1[4], ay1[4], ax2[4], ay2[4], aar[4];
    bool val[4];
#pragma unroll
    for (int k = 0; k < 4; ++k) {
        int a = base + k * 256 + t;
        val[k] = (a < A);
        float4 ab = ((const float4*)anchors)[val[k] ? a : 0];
        ax1[k] = val[k] ? ab.x : -3.0e38f;   // degenerate -> inter==+0, q==+0
        ay1[k] = val[k] ? ab.y : -3.0e38f;
        ax2[k] = val[k] ? ab.z : -3.0e38f;
        ay2[k] = val[k] ? ab.w : -3.0e38f;
        aar[k] = box_area(ax1[k], ay1[k], ax2[k], ay2[k]);
    }

    const float4* gtb = (const float4*)gt + (size_t)b * G;
    const float* gas = gab + b * G;

    float vmax[4] = {0.0f, 0.0f, 0.0f, 0.0f};
    int amax[4] = {g0, g0, g0, g0};        // first g of this half's range

#pragma unroll 8
    for (int gg = 0; gg < 32; ++gg) {
        const int g = g0 + gg;
        const int gv = vindex(g);              // VMEM broadcast (L1-hot)
        const float4 gb = gtb[gv];
        const float ga = gas[gv];
        float m = 0.0f;
#pragma unroll
        for (int k = 0; k < 4; ++k) {
            float inter = inter_area(gb.x, gb.y, gb.z, gb.w,
                                     ax1[k], ay1[k], ax2[k], ay2[k]);
            float denom = __fsub_rn(__fadd_rn(ga, aar[k]), inter);
            float q = div_rn(inter, denom);
            if constexpr (STORE) {
                if (q > vmax[k]) { vmax[k] = q; amax[k] = g; }  // first-max
            }
            m = fmaxf(m, q);
        }
        m = wave_max_lane63(m);
        if ((t & 63) == 63)
            atomicMax(&sred[gg], __float_as_uint(m));
    }

    if constexpr (STORE) {
#pragma unroll
        for (int k = 0; k < 4; ++k) {
            if (!val[k]) continue;
            size_t idx = (size_t)b * A + (base + k * 256 + t);
            // key: monotone in q (q>=0), ties -> larger ~amax = smaller amax
            unsigned long long key =
                ((unsigned long long)__float_as_uint(vmax[k]) << 32) |
                (unsigned int)(~amax[k]);
            atomicMax(&packed[idx], key);
        }
    }

    __syncthreads();
    if (t < 32) {
        atomicMax(&hpg[b * G + g0 + t], sred[t]);
        if constexpr (STORE)
            sredg[(size_t)((b * nchunks + blockIdx.x) * 2 + blockIdx.y) * 32 + t]
                = sred[t];
    }
}

// Pass 2 (fused): E[g] = (sred_halfblk[g]==hpg[g]) via SALU (both halves);
// rare set bits -> bit-exact recompute OR'd into pu; else pure threshold
// pass on unpacked (vmax, amax). Grid: (nchunks, B), block 256.
__global__ __launch_bounds__(256, 8)
void pass2_lite(const float* __restrict__ gt,
                const float* __restrict__ anchors,
                const float* __restrict__ gab,
                const unsigned int* __restrict__ hpg,
                const unsigned int* __restrict__ sredg,
                const unsigned long long* __restrict__ packed,
                float* __restrict__ out_idx,
                float* __restrict__ out_val,
                int A, int nchunks) {
    const int b = blockIdx.y;
    const int t = threadIdx.x;
    const int base = blockIdx.x * 1024;

    const unsigned int* sb =
        sredg + (size_t)(b * nchunks + blockIdx.x) * 2 * 32;   // halves adjacent
    const unsigned int* hb = hpg + b * G;

    // E: block-uniform (SALU) 64-bit mask of g's whose half-block max == global
    unsigned long long E = 0ull;
#pragma unroll 16
    for (int g = 0; g < G; ++g)
        E |= (sb[g] == hb[g]) ? (1ull << g) : 0ull;

    bool pu[4] = {false, false, false, false};

    if (E != 0ull) {                    // rare; block-uniform branch
        const float4* gtb = (const float4*)gt + (size_t)b * G;
        const float* gas = gab + b * G;
        float ax1[4], ay1[4], ax2[4], ay2[4], aar[4];
#pragma unroll
        for (int k = 0; k < 4; ++k) {
            int a = base + k * 256 + t;
            bool v = (a < A);
            float4 ab = ((const float4*)anchors)[v ? a : 0];
            ax1[k] = v ? ab.x : -3.0e38f;
            ay1[k] = v ? ab.y : -3.0e38f;
            ax2[k] = v ? ab.z : -3.0e38f;
            ay2[k] = v ? ab.w : -3.0e38f;
            aar[k] = box_area(ax1[k], ay1[k], ax2[k], ay2[k]);
        }
        unsigned long long e = E;
        while (e) {
            int g = __builtin_ctzll(e);
            e &= e - 1;
            float4 gb = gtb[g];
            float ga = gas[g];
            float hgf = __uint_as_float(hb[g]);
#pragma unroll
            for (int k = 0; k < 4; ++k) {
                float inter = inter_area(gb.x, gb.y, gb.z, gb.w,
                                         ax1[k], ay1[k], ax2[k], ay2[k]);
                float denom = __fsub_rn(__fadd_rn(ga, aar[k]), inter);
                float q = div_rn(inter, denom);
                pu[k] = pu[k] | (q == hgf);
            }
        }
    }

#pragma unroll
    for (int k = 0; k < 4; ++k) {
        int a = base + k * 256 + t;
        if (a >= A) continue;
        size_t idx = (size_t)b * A + a;
        unsigned long long p = packed[idx];
        float vm = __uint_as_float((unsigned int)(p >> 32));
        int am = (int)(~(unsigned int)p);
        int m;
        if (pu[k]) {
            m = am;                          // low-quality match recovery
        } else if (vm < 0.4f) {
            m = -1;                          // BELOW_LOW_QUALITY
        } else if (vm < 0.5f) {
            m = -2;                          // BETWEEN_THRESHOLDS
        } else {
            m = am;
        }
        out_idx[idx] = (float)m;
        out_val[idx] = vm;
    }
}

// Fallback pass 2 (R10 exact form): full recompute. Used when ws too small.
__global__ __launch_bounds__(256, 8)
void pass2_match(const float* __restrict__ gt,
                 const float* __restrict__ anchors,
                 const float* __restrict__ gab,
                 const unsigned int* __restrict__ hpg,
                 float* __restrict__ out_idx,
                 float* __restrict__ out_val, int A) {
    const int b = blockIdx.y;
    const int t = threadIdx.x;
    const int base = blockIdx.x * 512;

    float ax1[2], ay1[2], ax2[2], ay2[2], aar[2];
    bool val[2];
#pragma unroll
    for (int k = 0; k < 2; ++k) {
        int a = base + k * 256 + t;
        val[k] = (a < A);
        float4 ab = ((const float4*)anchors)[val[k] ? a : 0];
        ax1[k] = ab.x; ay1[k] = ab.y; ax2[k] = ab.z; ay2[k] = ab.w;
        aar[k] = box_area(ab.x, ab.y, ab.z, ab.w);
    }

    const float4* gtb = (const float4*)gt + (size_t)b * G;
    const float* gas = gab + b * G;
    const unsigned int* hpgb = hpg + b * G;

    float vmax[2] = {0.0f, 0.0f};
    int amax[2] = {0, 0};
    bool pu[2] = {false, false};
#pragma unroll 8
    for (int g = 0; g < G; ++g) {
        float4 gb = gtb[g];
        float ga = gas[g];
        float hg = __uint_as_float(hpgb[g]);
#pragma unroll
        for (int k = 0; k < 2; ++k) {
            float inter = inter_area(gb.x, gb.y, gb.z, gb.w,
                                     ax1[k], ay1[k], ax2[k], ay2[k]);
            float denom = __fsub_rn(__fadd_rn(ga, aar[k]), inter);
            float q = div_rn(inter, denom);
            pu[k] = pu[k] | (q == hg);
            if (q > vmax[k]) { vmax[k] = q; amax[k] = g; }
        }
    }

#pragma unroll
    for (int k = 0; k < 2; ++k) {
        if (!val[k]) continue;
        int m;
        if (pu[k]) m = amax[k];
        else if (vmax[k] < 0.4f) m = -1;
        else if (vmax[k] < 0.5f) m = -2;
        else m = amax[k];
        size_t o = (size_t)b * A + (base + k * 256 + t);
        out_idx[o] = (float)m;
        out_val[o] = vmax[k];
    }
}

extern "C" void kernel_launch(void* const* d_in, const int* in_sizes, int n_in,
                              void* d_out, int out_size, void* d_ws, size_t ws_size,
                              hipStream_t stream) {
    const float* gt = (const float*)d_in[0];
    const float* anchors = (const float*)d_in[1];
    const int BG = in_sizes[0] / 4;   // B*G = 512
    const int B = BG / G;             // 8
    const int A = in_sizes[1] / 4;    // 120000

    const int nchunks = (A + 1023) / 1024;

    // ws layout (u32 units):
    // [0,512) hpg | [512,1024) ga | [1024, +nchunks*B*64) sredg |
    // then (8-byte aligned) packed u64[B*A]
    unsigned int* ws = (unsigned int*)d_ws;
    unsigned int* hpg = ws;
    float* gab = (float*)(ws + 512);
    unsigned int* sredg = ws + 1024;
    size_t poff = 1024 + (size_t)nchunks * B * G;
    poff = (poff + 1) & ~(size_t)1;                    // align to u64
    unsigned long long* packed = (unsigned long long*)(ws + poff);
    const size_t need = (poff + 2 * (size_t)B * A) * 4;
    const bool fused = (ws_size >= need);

    float* out_idx = (float*)d_out;
    float* out_val = out_idx + (size_t)B * A;

    k_init<<<(BG + 255) / 256, 256, 0, stream>>>(gt, hpg, gab, BG);

    dim3 g1(nchunks, 2, B);
    if (fused) {
        hipMemsetAsync(packed, 0, (size_t)B * A * 8, stream);  // keys all > 0
        pass1_k<true><<<g1, 256, 0, stream>>>(gt, anchors, gab, hpg, sredg,
                                              packed, A, nchunks);
        dim3 g2(nchunks, B);
        pass2_lite<<<g2, 256, 0, stream>>>(gt, anchors, gab, hpg, sredg,
                                           packed, out_idx, out_val,
                                           A, nchunks);
    } else {
        pass1_k<false><<<g1, 256, 0, stream>>>(gt, anchors, gab, hpg, sredg,
                                               packed, A, nchunks);
        dim3 g2f((A + 511) / 512, B);
        pass2_match<<<g2f, 256, 0, stream>>>(gt, anchors, gab, hpg,
                                             out_idx, out_val, A);
    }
}